// Round 3
// baseline (4017.445 us; speedup 1.0000x reference)
//
#include <hip/hip_runtime.h>
#include <math.h>

#define TOK_TOTAL (8*4096)
#define EPS 0.01f
#define RIDGE 1e-4f
#define MAXNORM 3.925724783138660f
#define PADE5_TH 1.880152677804762f
#define PADE3_TH 0.4258730016922831f

// ---------------------------------------------------------------------------
// K1: hidden activations tA/tB = silu(c @ W1^T + b1) for a chunk of tokens.
// block=256 handles 64 tokens x 128 hidden units (64 for A-MLP, 64 for B-MLP).
// ---------------------------------------------------------------------------
__global__ __launch_bounds__(256) void k_hidden(
    const float* __restrict__ c,
    const float* __restrict__ A_W1, const float* __restrict__ A_b1,
    const float* __restrict__ B_W1, const float* __restrict__ B_b1,
    float* __restrict__ tA, float* __restrict__ tB, int ntok)
{
  __shared__ __align__(16) float csh[64][68];
  const int t = threadIdx.x;
  const int tok0 = blockIdx.x * 64;

  for (int e = t * 4; e < 4096; e += 1024) {
    int tt = e >> 6, k = e & 63;
    float4 v = make_float4(0.f, 0.f, 0.f, 0.f);
    if (tok0 + tt < ntok) v = *(const float4*)&c[(size_t)(tok0 + tt) * 64 + k];
    *(float4*)&csh[tt][k] = v;
  }
  __syncthreads();

  const int h = t & 127;        // 0..63 -> A-MLP, 64..127 -> B-MLP
  const int half = t >> 7;      // token half
  const int hh = h & 63;
  const float* Wrow = (h < 64) ? &A_W1[hh * 64] : &B_W1[hh * 64];
  const float bias = (h < 64) ? A_b1[hh] : B_b1[hh];
  float* dst = (h < 64) ? tA : tB;

  float4 w4[16];
#pragma unroll
  for (int k = 0; k < 16; ++k) w4[k] = *(const float4*)&Wrow[k * 4];

  for (int tt = half * 32; tt < half * 32 + 32; ++tt) {
    float acc = bias;
#pragma unroll
    for (int k = 0; k < 16; ++k) {
      float4 cv = *(const float4*)&csh[tt][k * 4];
      acc += w4[k].x * cv.x + w4[k].y * cv.y + w4[k].z * cv.z + w4[k].w * cv.w;
    }
    float sv = acc / (1.0f + expf(-acc));   // silu, precise exp
    if (tok0 + tt < ntok) dst[(size_t)(tok0 + tt) * 64 + hh] = sv;
  }
}

// ---------------------------------------------------------------------------
// K2: out[tok][o] = tact[tok][:] @ W2[o][:] + b2[o]  (minus EPS on diag if A)
// block=256: 64-token x 128-output tile; per-thread 4x8; weights via L1/L2.
// ---------------------------------------------------------------------------
template <bool SUBEPS>
__global__ __launch_bounds__(256) void k_w2gemm(
    const float* __restrict__ tact, const float* __restrict__ W2,
    const float* __restrict__ b2, float* __restrict__ outw,
    int Nout, int ntok)
{
  __shared__ __align__(16) float tsh[64][68];
  const int t = threadIdx.x;
  const int tok0 = blockIdx.x * 64;
  const int o0 = blockIdx.y * 128;

  for (int e = t * 4; e < 4096; e += 1024) {
    int tt = e >> 6, k = e & 63;
    float4 v = make_float4(0.f, 0.f, 0.f, 0.f);
    if (tok0 + tt < ntok) v = *(const float4*)&tact[(size_t)(tok0 + tt) * 64 + k];
    *(float4*)&tsh[tt][k] = v;
  }
  __syncthreads();

  const int ty = t >> 4, tx = t & 15;
  const int toks = ty * 4;
  const int outs = o0 + tx * 8;

  float acc[4][8];
#pragma unroll
  for (int r = 0; r < 4; ++r)
#pragma unroll
    for (int q = 0; q < 8; ++q) acc[r][q] = 0.f;

#pragma unroll 4
  for (int kg = 0; kg < 64; kg += 4) {
    float4 a[4];
#pragma unroll
    for (int r = 0; r < 4; ++r) a[r] = *(const float4*)&tsh[toks + r][kg];
    float4 w[8];
#pragma unroll
    for (int q = 0; q < 8; ++q) w[q] = *(const float4*)&W2[(size_t)(outs + q) * 64 + kg];
#pragma unroll
    for (int r = 0; r < 4; ++r)
#pragma unroll
      for (int q = 0; q < 8; ++q)
        acc[r][q] += a[r].x * w[q].x + a[r].y * w[q].y + a[r].z * w[q].z + a[r].w * w[q].w;
  }

#pragma unroll
  for (int r = 0; r < 4; ++r) {
    int row = tok0 + toks + r;
    if (row >= ntok) continue;
    float tmp[8];
#pragma unroll
    for (int q = 0; q < 8; ++q) {
      int o = outs + q;
      float v = acc[r][q] + b2[o];
      if (SUBEPS && (o % 33 == 0)) v -= EPS;   // o = i*32+j, diag <=> o%33==0
      tmp[q] = v;
    }
    *(float4*)&outw[(size_t)row * Nout + outs] = *(float4*)&tmp[0];
    *(float4*)&outw[(size_t)row * Nout + outs + 4] = *(float4*)&tmp[4];
  }
}

// ---------------------------------------------------------------------------
// 32x32 matmul in LDS, stride 40 floats, 256 threads, 1x4 tile per thread.
// Caller must __syncthreads() before and after.
// ---------------------------------------------------------------------------
__device__ __forceinline__ void mm32(float* __restrict__ d, const float* __restrict__ a,
                                     const float* __restrict__ b, int t)
{
  const int i = t >> 3, j0 = (t & 7) << 2;
  float4 acc = make_float4(0.f, 0.f, 0.f, 0.f);
#pragma unroll
  for (int k = 0; k < 32; k += 4) {
    const float4 av = *(const float4*)&a[i * 40 + k];
    const float4 b0 = *(const float4*)&b[(k + 0) * 40 + j0];
    const float4 b1 = *(const float4*)&b[(k + 1) * 40 + j0];
    const float4 b2 = *(const float4*)&b[(k + 2) * 40 + j0];
    const float4 b3 = *(const float4*)&b[(k + 3) * 40 + j0];
    acc.x += av.x * b0.x + av.y * b1.x + av.z * b2.x + av.w * b3.x;
    acc.y += av.x * b0.y + av.y * b1.y + av.z * b2.y + av.w * b3.y;
    acc.z += av.x * b0.z + av.y * b1.z + av.z * b2.z + av.w * b3.z;
    acc.w += av.x * b0.w + av.y * b1.w + av.z * b2.w + av.w * b3.w;
  }
  *(float4*)&d[i * 40 + j0] = acc;
}

// ---------------------------------------------------------------------------
// K3: per-token expm (JAX pade3/5/7 + scaling/squaring), solves, h_next.
// One block (256 thr) per token. Matches jax.scipy.linalg.expm fp32 path:
//   idx = digitize(||Adt||_1, [0.42587, 1.88015]) -> pade{3,5,7}
//   s = max(0, floor(log2(||Adt||_1 / 3.92572)))
// ---------------------------------------------------------------------------
__global__ __launch_bounds__(256, 4) void k_token(
    const float* __restrict__ Aws,   // [ct][1024] = mlpA - eps*I
    const float* __restrict__ Bws,   // [ct][512]
    const float* __restrict__ hg,    // [TOK][32]
    const float* __restrict__ ug,    // [TOK][16]
    const float* __restrict__ dtg,   // [8]
    const float* __restrict__ uW,    // [16][16]
    const float* __restrict__ ub,    // [16]
    float* __restrict__ hout,        // [TOK][32]
    int base)
{
  const int t = threadIdx.x;
  const int tloc = blockIdx.x;
  const int tg = base + tloc;

  __shared__ __align__(16) float SA[1280];
  __shared__ __align__(16) float W0[1280];   // Ms / R
  __shared__ __align__(16) float W1b[1280];  // M2 / Wpoly / R'
  __shared__ __align__(16) float W2b[1280];  // M4 / V / Q / G
  __shared__ __align__(16) float W3b[1280];  // M6
  __shared__ __align__(16) float W4b[1280];  // U / P / X
  __shared__ __align__(16) float Bm[640];    // 32x20
  __shared__ __align__(16) float uWs[256];
  __shared__ __align__(16) float u_sh[16];
  __shared__ __align__(16) float h_sh[32];
  __shared__ float up_sh[16];
  __shared__ float bu_sh[32];
  __shared__ float rhs_sh[32];
  __shared__ int perm[32];
  __shared__ float s_fac;
  __shared__ int s_nsq;
  __shared__ int s_idx;

  // ---- loads ----
  {
    int e = t * 4, i = e >> 5, k = e & 31;
    float4 v = *(const float4*)&Aws[(size_t)tloc * 1024 + e];
    *(float4*)&SA[i * 40 + k] = v;
  }
  if (t < 128) {
    int e = t * 4, i = e >> 4, p = e & 15;
    *(float4*)&Bm[i * 20 + p] = *(const float4*)&Bws[(size_t)tloc * 512 + e];
  }
  if (t >= 128 && t < 192) {
    int e = (t - 128) * 4;
    *(float4*)&uWs[e] = *(const float4*)&uW[e];
  }
  if (t >= 192 && t < 200) {
    int e = (t - 192) * 4;
    *(float4*)&h_sh[e] = *(const float4*)&hg[(size_t)tg * 32 + e];
  }
  if (t >= 200 && t < 204) {
    int e = (t - 200) * 4;
    *(float4*)&u_sh[e] = *(const float4*)&ug[(size_t)tg * 16 + e];
  }
  const float dtv = dtg[tg >> 12];
  __syncthreads();

  // ---- L1 norm of A*dt (threads 0-31), u_proj (threads 32-47) ----
  if (t < 32) {
    float sum = 0.f;
    for (int i = 0; i < 32; ++i) sum += fabsf(SA[i * 40 + t] * dtv);
    for (int m = 16; m; m >>= 1) sum = fmaxf(sum, __shfl_xor(sum, m));
    if (t == 0) {
      int s = 0;
      if (sum > MAXNORM) {
        s = (int)floorf(log2f(sum / MAXNORM));   // JAX: max(0, floor(log2(norm/theta7)))
        if (s < 0) s = 0;
      }
      s_nsq = s;
      s_fac = exp2f(-(float)s);                   // exact power of two
      s_idx = (sum >= PADE3_TH ? 1 : 0) + (sum >= PADE5_TH ? 1 : 0);
    }
  } else if (t >= 32 && t < 48) {
    int p = t - 32;
    float acc = ub[p];
    for (int k = 0; k < 16; ++k) acc += uWs[p * 16 + k] * u_sh[k];
    up_sh[p] = acc;
  }
  __syncthreads();

  // ---- Ms = (A*dt) * 2^-s   (round A*dt first, like JAX, then exact scale) ----
  {
    float fac = s_fac;
    int e = t * 4, i = e >> 5, k = e & 31;
    float4 v = *(const float4*)&SA[i * 40 + k];
    v.x = (v.x * dtv) * fac; v.y = (v.y * dtv) * fac;
    v.z = (v.z * dtv) * fac; v.w = (v.w * dtv) * fac;
    *(float4*)&W0[i * 40 + k] = v;
  }
  const int pidx = s_idx;   // block-uniform (written before the prior barrier's release)
  __syncthreads();

  // ---- Pade powers (block-uniform branches) ----
  mm32(W1b, W0, W0, t);  __syncthreads();                      // M2
  if (pidx >= 1) { mm32(W2b, W1b, W1b, t); __syncthreads(); }  // M4 = M2@M2
  if (pidx == 2) { mm32(W3b, W2b, W1b, t); __syncthreads(); }  // M6 = M4@M2

  // ---- poly (JAX coefficient sets):
  //   pade3: U=A@(M2+60I)            V=12 M2+120I
  //   pade5: U=A@(M4+420M2+15120I)   V=30 M4+3360 M2+30240I
  //   pade7: U=A@(M6+1512M4+277200M2+8648640I)
  //          V=56 M6+25200 M4+1995840 M2+17297280I
  //   Wpoly -> W1b, V -> W2b
  {
    int e = t * 4, i = e >> 5, k0 = e & 31;
    float4 m2 = *(const float4*)&W1b[i * 40 + k0];
    float4 w, v;
    float wI, vI;
    if (pidx == 0) {
      w = m2;
      v.x = 12.f * m2.x; v.y = 12.f * m2.y; v.z = 12.f * m2.z; v.w = 12.f * m2.w;
      wI = 60.f; vI = 120.f;
    } else if (pidx == 1) {
      float4 m4 = *(const float4*)&W2b[i * 40 + k0];
      w.x = m4.x + 420.f * m2.x;  w.y = m4.y + 420.f * m2.y;
      w.z = m4.z + 420.f * m2.z;  w.w = m4.w + 420.f * m2.w;
      v.x = 30.f * m4.x + 3360.f * m2.x;  v.y = 30.f * m4.y + 3360.f * m2.y;
      v.z = 30.f * m4.z + 3360.f * m2.z;  v.w = 30.f * m4.w + 3360.f * m2.w;
      wI = 15120.f; vI = 30240.f;
    } else {
      float4 m4 = *(const float4*)&W2b[i * 40 + k0];
      float4 m6 = *(const float4*)&W3b[i * 40 + k0];
      w.x = m6.x + 1512.f * m4.x + 277200.f * m2.x;
      w.y = m6.y + 1512.f * m4.y + 277200.f * m2.y;
      w.z = m6.z + 1512.f * m4.z + 277200.f * m2.z;
      w.w = m6.w + 1512.f * m4.w + 277200.f * m2.w;
      v.x = 56.f * m6.x + 25200.f * m4.x + 1995840.f * m2.x;
      v.y = 56.f * m6.y + 25200.f * m4.y + 1995840.f * m2.y;
      v.z = 56.f * m6.z + 25200.f * m4.z + 1995840.f * m2.z;
      v.w = 56.f * m6.w + 25200.f * m4.w + 1995840.f * m2.w;
      wI = 8648640.f; vI = 17297280.f;
    }
    w.x += (i == k0 + 0) ? wI : 0.f;  v.x += (i == k0 + 0) ? vI : 0.f;
    w.y += (i == k0 + 1) ? wI : 0.f;  v.y += (i == k0 + 1) ? vI : 0.f;
    w.z += (i == k0 + 2) ? wI : 0.f;  v.z += (i == k0 + 2) ? vI : 0.f;
    w.w += (i == k0 + 3) ? wI : 0.f;  v.w += (i == k0 + 3) ? vI : 0.f;
    *(float4*)&W1b[i * 40 + k0] = w;
    *(float4*)&W2b[i * 40 + k0] = v;
  }
  __syncthreads();

  mm32(W4b, W0, W1b, t);  // U = Ms @ Wpoly
  __syncthreads();

  // ---- P = U+V -> W4b, Q = V-U -> W2b; init perm ----
  {
    int e = t * 4, i = e >> 5, k0 = e & 31;
    float4 uu = *(const float4*)&W4b[i * 40 + k0];
    float4 vv = *(const float4*)&W2b[i * 40 + k0];
    float4 p, q;
    p.x = uu.x + vv.x; p.y = uu.y + vv.y; p.z = uu.z + vv.z; p.w = uu.w + vv.w;
    q.x = vv.x - uu.x; q.y = vv.y - uu.y; q.z = vv.z - uu.z; q.w = vv.w - uu.w;
    *(float4*)&W4b[i * 40 + k0] = p;
    *(float4*)&W2b[i * 40 + k0] = q;
  }
  if (t < 32) perm[t] = t;
  __syncthreads();

  // ---- LU1: factor Q (W2b) w/ partial pivot (perm), forward-elim P (W4b) ----
  for (int k = 0; k < 32; ++k) {
    if (t < 32) {
      float v = -1.f;
      if (t >= k) v = fabsf(W2b[perm[t] * 40 + k]);
      int idx = t;
      for (int m = 16; m; m >>= 1) {
        float ov = __shfl_xor(v, m);
        int oi = __shfl_xor(idx, m);
        if (ov > v || (ov == v && oi < idx)) { v = ov; idx = oi; }
      }
      if (t == 0 && idx != k) { int tmp = perm[k]; perm[k] = perm[idx]; perm[idx] = tmp; }
    }
    __syncthreads();
    {
      int r = t >> 3;
      if (r > k) {
        int pr = perm[r], pk = perm[k];
        float m = W2b[pr * 40 + k] / W2b[pk * 40 + k];
        int j0 = (t & 7) * 8;
#pragma unroll
        for (int jj = 0; jj < 8; ++jj) {
          int j = j0 + jj;
          if (j > k && j < 32)       W2b[pr * 40 + j] -= m * W2b[pk * 40 + j];
          else if (j >= 32)          W4b[pr * 40 + j - 32] -= m * W4b[pk * 40 + j - 32];
        }
      }
    }
    __syncthreads();
  }
  // ---- back-substitution, divide-deferred: 1 barrier/step ----
  for (int k = 31; k > 0; --k) {
    int r = t >> 3;
    if (r < k) {
      int pr = perm[r], pk = perm[k];
      float f = W2b[pr * 40 + k] / W2b[pk * 40 + k];
      int j0 = (t & 7) * 4;
#pragma unroll
      for (int jj = 0; jj < 4; ++jj)
        W4b[pr * 40 + j0 + jj] -= f * W4b[pk * 40 + j0 + jj];
    }
    __syncthreads();
  }
  // ---- final diagonal scale + unpermute X -> W0 (R) ----
  {
    int e = t * 4, i = e >> 5, j = e & 31;
    int pi = perm[i];
    float dinv = 1.0f / W2b[pi * 40 + i];
    float4 v = *(const float4*)&W4b[pi * 40 + j];
    v.x *= dinv; v.y *= dinv; v.z *= dinv; v.w *= dinv;
    *(float4*)&W0[i * 40 + j] = v;
  }
  __syncthreads();

  // ---- squarings ----
  float* cur = W0;
  float* oth = W1b;
  const int ns = s_nsq;
  for (int q = 0; q < ns; ++q) {
    mm32(oth, cur, cur, t);
    __syncthreads();
    float* tmp = cur; cur = oth; oth = tmp;
  }

  // ---- bu = Bmat @ up;  G = A + ridge*I -> W2b;  perm reinit ----
  if (t < 32) {
    float acc = 0.f;
    for (int p = 0; p < 16; ++p) acc += Bm[t * 20 + p] * up_sh[p];
    bu_sh[t] = acc;
    perm[t] = t;
  }
  {
    int e = t * 4, i = e >> 5, k0 = e & 31;
    float4 v = *(const float4*)&SA[i * 40 + k0];
    v.x += (i == k0 + 0) ? RIDGE : 0.f;
    v.y += (i == k0 + 1) ? RIDGE : 0.f;
    v.z += (i == k0 + 2) ? RIDGE : 0.f;
    v.w += (i == k0 + 3) ? RIDGE : 0.f;
    *(float4*)&W2b[i * 40 + k0] = v;
  }
  __syncthreads();

  // ---- rhs = (expA - I) @ bu ----
  if (t < 32) {
    float acc = 0.f;
    for (int j = 0; j < 32; ++j) acc += cur[t * 40 + j] * bu_sh[j];
    rhs_sh[t] = acc - bu_sh[t];
  }
  __syncthreads();

  // ---- LU2: factor G (W2b) with rhs vector ----
  for (int k = 0; k < 32; ++k) {
    if (t < 32) {
      float v = -1.f;
      if (t >= k) v = fabsf(W2b[perm[t] * 40 + k]);
      int idx = t;
      for (int m = 16; m; m >>= 1) {
        float ov = __shfl_xor(v, m);
        int oi = __shfl_xor(idx, m);
        if (ov > v || (ov == v && oi < idx)) { v = ov; idx = oi; }
      }
      if (t == 0 && idx != k) { int tmp = perm[k]; perm[k] = perm[idx]; perm[idx] = tmp; }
    }
    __syncthreads();
    {
      int r = t >> 3;
      if (r > k) {
        int pr = perm[r], pk = perm[k];
        float m = W2b[pr * 40 + k] / W2b[pk * 40 + k];
        int j0 = (t & 7) * 8;
        if (j0 < 32) {
#pragma unroll
          for (int jj = 0; jj < 8; ++jj) {
            int j = j0 + jj;
            if (j > k) W2b[pr * 40 + j] -= m * W2b[pk * 40 + j];
          }
        } else if (j0 == 32) {
          rhs_sh[pr] -= m * rhs_sh[pk];
        }
      }
    }
    __syncthreads();
  }
  // ---- back-substitution on vector, divide-deferred: 1 barrier/step ----
  for (int k = 31; k > 0; --k) {
    if (t < k) {
      int pt = perm[t], pk = perm[k];
      rhs_sh[pt] -= (W2b[pt * 40 + k] / W2b[pk * 40 + k]) * rhs_sh[pk];
    }
    __syncthreads();
  }

  // ---- h_next = expA @ h + x   (x_t = y_{perm[t]} / U[t][t] inline) ----
  if (t < 32) {
    int pt = perm[t];
    float acc = rhs_sh[pt] / W2b[pt * 40 + t];
    for (int j = 0; j < 32; ++j) acc += cur[t * 40 + j] * h_sh[j];
    hout[(size_t)tg * 32 + t] = acc;
  }
}

// ---------------------------------------------------------------------------
extern "C" void kernel_launch(void* const* d_in, const int* in_sizes, int n_in,
                              void* d_out, int out_size, void* d_ws, size_t ws_size,
                              hipStream_t stream)
{
  const float* h    = (const float*)d_in[0];
  const float* u    = (const float*)d_in[1];
  const float* c    = (const float*)d_in[2];
  const float* dt   = (const float*)d_in[3];
  const float* A_W1 = (const float*)d_in[4];
  const float* A_b1 = (const float*)d_in[5];
  const float* A_W2 = (const float*)d_in[6];
  const float* A_b2 = (const float*)d_in[7];
  const float* B_W1 = (const float*)d_in[8];
  const float* B_b1 = (const float*)d_in[9];
  const float* B_W2 = (const float*)d_in[10];
  const float* B_b2 = (const float*)d_in[11];
  const float* uW   = (const float*)d_in[12];
  const float* ub   = (const float*)d_in[13];
  float* out = (float*)d_out;

  // per-token ws: tA(64) + tB(64) + A(1024) + Bmat(512) floats = 6656 B
  const size_t per_tok = 6656;
  int ct = (int)((ws_size / per_tok) & ~(size_t)63);
  if (ct > TOK_TOTAL) ct = TOK_TOTAL;
  if (ct < 64) ct = 64;   // assume ws is at least ~0.5 MB

  for (int base = 0; base < TOK_TOTAL; base += ct) {
    int n = TOK_TOTAL - base; if (n > ct) n = ct;
    float* tA = (float*)d_ws;
    float* tB = tA + (size_t)ct * 64;
    float* Aw = tB + (size_t)ct * 64;
    float* Bw = Aw + (size_t)ct * 1024;

    k_hidden<<<n / 64, 256, 0, stream>>>(c + (size_t)base * 64,
                                         A_W1, A_b1, B_W1, B_b1, tA, tB, n);
    k_w2gemm<true ><<<dim3(n / 64, 8), 256, 0, stream>>>(tA, A_W2, A_b2, Aw, 1024, n);
    k_w2gemm<false><<<dim3(n / 64, 4), 256, 0, stream>>>(tB, B_W2, B_b2, Bw, 512, n);
    k_token<<<n, 256, 0, stream>>>(Aw, Bw, h, u, dt, uW, ub, out, base);
  }
}